// Round 8
// baseline (1409.009 us; speedup 1.0000x reference)
//
#include <hip/hip_runtime.h>
#include <hip/hip_bf16.h>
#include <type_traits>

#define T_    1000
#define NB    256
#define HH    64
#define GG    256

typedef float f32x4 __attribute__((ext_vector_type(4)));
typedef __bf16 bf16x8 __attribute__((ext_vector_type(8)));

// Barrier that does NOT drain vmcnt (plain __syncthreads emits s_waitcnt vmcnt(0)
// which would stall on global h-stores and x-prefetch every step).
__device__ __forceinline__ void barrier_lds() {
    asm volatile("s_waitcnt lgkmcnt(0)\n\ts_barrier" ::: "memory");
}

__device__ __forceinline__ float fast_sigmoid(float x) {
    float e = __expf(-x);
    return __builtin_amdgcn_rcpf(1.f + e);
}
__device__ __forceinline__ float fast_tanh(float x) {
    x = fmaxf(x, -15.f);
    float e = __expf(-2.f * x);
    return (1.f - e) * __builtin_amdgcn_rcpf(1.f + e);
}
__device__ __forceinline__ float bf2f(unsigned short u) {
    return __builtin_bit_cast(float, (unsigned)u << 16);
}

// ---------------------------------------------------------------- weight prep
__global__ void prep_w(const float* __restrict__ wihf, const float* __restrict__ wihr,
                       const float* __restrict__ whh, const float* __restrict__ bih,
                       const float* __restrict__ bhh,
                       __bf16* __restrict__ w0H, __bf16* __restrict__ w0L,
                       __bf16* __restrict__ wrH, __bf16* __restrict__ whH,
                       float* __restrict__ bias, float* __restrict__ w0f) {
    int i = blockIdx.x * 256 + threadIdx.x;
    if (i < 2 * GG * 32) {
        int k = i & 31, gd = i >> 5;
        float w = (k < 22) ? wihf[gd * 22 + k] : 0.f;
        __bf16 h = (__bf16)w;
        w0H[i] = h; w0L[i] = (__bf16)(w - (float)h);
        w0f[i] = w;
    }
    if (i < 3 * 2 * GG * 128) wrH[i] = (__bf16)wihr[i];
    if (i < 4 * 2 * GG * HH)  whH[i] = (__bf16)whh[i];
    if (i < 4 * 2 * GG)       bias[i] = bih[i] + bhh[i];
}

// ---------------------------------------------------------------- x prep, hi/lo bf16 planes (layer 0)
__global__ __launch_bounds__(256) void prep_x_ps(const float* __restrict__ x,
                                                 __bf16* __restrict__ xhi,
                                                 __bf16* __restrict__ xlo) {
    const int b = blockIdx.x;
    __shared__ float xs[22][104];
    for (int tc = 0; tc < 10; ++tc) {
        const int t0 = tc * 100;
        __syncthreads();
        for (int i = threadIdx.x; i < 22 * 100; i += 256) {
            int k = i / 100, t = i - k * 100;
            xs[k][t] = x[((size_t)b * 22 + k) * T_ + t0 + t];
        }
        __syncthreads();
        for (int i = threadIdx.x; i < 100 * 4; i += 256) {
            int t = i >> 2, p = i & 3;
            bf16x8 vh, vl;
            #pragma unroll
            for (int j = 0; j < 8; ++j) {
                int k = p * 8 + j;
                float f = (k < 22) ? xs[k][t] : 0.f;
                __bf16 h = (__bf16)f;
                vh[j] = h;
                vl[j] = (__bf16)(f - (float)h);
            }
            *(bf16x8*)(xhi + ((size_t)b * T_ + t0 + t) * 32 + p * 8) = vh;
            *(bf16x8*)(xlo + ((size_t)b * T_ + t0 + t) * 32 + p * 8) = vl;
        }
    }
}

// ---------------------------------------------------------------- x prep single bf16 plane (fallback)
__global__ __launch_bounds__(256) void prep_x_b(const float* __restrict__ x,
                                                __bf16* __restrict__ xp) {
    const int b = blockIdx.x;
    __shared__ float xs[22][104];
    for (int tc = 0; tc < 10; ++tc) {
        const int t0 = tc * 100;
        __syncthreads();
        for (int i = threadIdx.x; i < 22 * 100; i += 256) {
            int k = i / 100, t = i - k * 100;
            xs[k][t] = x[((size_t)b * 22 + k) * T_ + t0 + t];
        }
        __syncthreads();
        for (int i = threadIdx.x; i < 100 * 4; i += 256) {
            int t = i >> 2, p = i & 3;
            bf16x8 v;
            #pragma unroll
            for (int j = 0; j < 8; ++j) {
                int k = p * 8 + j;
                v[j] = (k < 22) ? (__bf16)xs[k][t] : (__bf16)0.f;
            }
            *(bf16x8*)(xp + ((size_t)b * T_ + t0 + t) * 32 + p * 8) = v;
        }
    }
}

// ---------------------------------------------------------------- MFMA fused layer, r21: 1 chain/block, 16-step groups
// r14 retried WITHOUT work duplication: the MFMA M-rows 0-15 hold 16 TIMESTEPS
// of a single chain (r14 held 2x8 duplicated; r13/r15 held 2 chains x 8 steps).
// 512 blocks (256 batch x 2 dir), __launch_bounds__(256,2) -> 2 blocks/CU,
// 2 waves/SIMD from INDEPENDENT barrier domains: one block's ds/barrier/chain
// stalls are filled by the other block's issue (mechanism proven by r14, which
// paid 2x work for +20% time; here per-chain work is unchanged).
// Step<->row mapping uses the involution row = u ^ ((u&8)>>1) so the c-chain
// ownership order is quarters q0,q1,q3,q2: handoffs at u=3,11 are lane^16
// (r15-proven ds_swizzle 0x401F), at u=7,15 lane^32 via ds_bpermute (pull).
// Everything else is the r15 recipe: weights in registers, x double-buffered
// prefetch at u==0, deferred flush in next group's u==0 ds window, chained
// depth-2 R-MFMA (r20 proved the split hurts), P ping-pong by 16-step groups.
template<int KCH, bool L0, bool FIN>
__global__ __launch_bounds__(256, 2) void fused_scan1c(
    const __bf16* __restrict__ inA,   // (B,T,KCH*32) bf16 (hi plane if L0)
    const __bf16* __restrict__ inB,   // lo plane (iff L0)
    const __bf16* __restrict__ wihH,  // (2,256,KCH*32) bf16 hi
    const __bf16* __restrict__ wihL,  // same, lo (iff L0)
    const __bf16* __restrict__ whhH,  // (2,256,64) bf16
    const float*  __restrict__ bias,  // (2,256) f32
    __bf16* __restrict__ out,         // (B,T,128) bf16
    float* __restrict__ outF)         // (B,128) f32 last-t h (iff FIN)
{
    const int dir = blockIdx.y;
    const int bb = blockIdx.x;        // single chain per block
    const int tid = threadIdx.x;
    const int wv = tid >> 6, lane = tid & 63;
    const int j2 = lane & 15, q = lane >> 4;
    // A-row j2 carries step u_l within the 16-step group (involution)
    const int u_l = j2 ^ ((j2 & 8) >> 1);
    const int bpidx = (lane ^ 32) << 2;     // ds_bpermute byte index: pull lane^32
    constexpr int KIN = KCH * 32;

    __shared__ __align__(16) __bf16 hbuf[2][80]; // [parity][dim pad]

    const f32x4 Z4 = (f32x4){0.f, 0.f, 0.f, 0.f};

    bf16x8 wf[4][KCH], wfl[4][L0 ? KCH : 1];
    bf16x8 whf[4][2];
    float bgate[4];
    #pragma unroll
    for (int F = 0; F < 4; ++F) {
        const int g = (F * 4 + wv) * 16 + j2;
        bgate[F] = bias[dir * GG + g];
        #pragma unroll
        for (int ks = 0; ks < KCH; ++ks) {
            wf[F][ks] = *(const bf16x8*)(wihH + ((size_t)dir * GG + g) * KIN + ks * 32 + q * 8);
            if constexpr (L0)
                wfl[F][ks] = *(const bf16x8*)(wihL + ((size_t)dir * GG + g) * KIN + ks * 32 + q * 8);
        }
        #pragma unroll
        for (int ks = 0; ks < 2; ++ks)
            whf[F][ks] = *(const bf16x8*)(whhH + ((size_t)dir * GG + g) * HH + ks * 32 + q * 8);
    }
    if (tid < 64) hbuf[1][tid] = (__bf16)0.f;
    __syncthreads();

    // double-buffered x fragments: A holds even-group x, B holds odd-group x
    bf16x8 xfA[KCH], xfB[KCH];
    bf16x8 xlA[L0 ? KCH : 1], xlB[L0 ? KCH : 1];
    auto issue_x = [&](int grp, auto& dh, auto& dl) {
        int s = grp * 16 + u_l;
        if (s > T_ - 1) s = T_ - 1;
        int tt = dir ? (T_ - 1) - s : s;
        const __bf16* ph = inA + ((size_t)bb * T_ + tt) * KIN + q * 8;
        #pragma unroll
        for (int ks = 0; ks < KCH; ++ks)
            dh[ks] = *(const bf16x8*)(ph + ks * 32);
        if constexpr (L0) {
            const __bf16* pl = inB + ((size_t)bb * T_ + tt) * KIN + q * 8;
            #pragma unroll
            for (int ks = 0; ks < KCH; ++ks)
                dl[ks] = *(const bf16x8*)(pl + ks * 32);
        }
    };

    // ---- prologue: P for group 0 (+bias), then prefetch group 1
    f32x4 Pu[4], Pn[4];
    #pragma unroll
    for (int F = 0; F < 4; ++F) { Pu[F] = Z4; Pn[F] = Z4; }
    issue_x(0, xfA, xlA);
    #pragma unroll
    for (int ks = 0; ks < KCH; ++ks)
        #pragma unroll
        for (int F = 0; F < 4; ++F)
            Pu[F] = __builtin_amdgcn_mfma_f32_16x16x32_bf16(xfA[ks], wf[F][ks], Pu[F], 0, 0, 0);
    if constexpr (L0) {
        #pragma unroll
        for (int ks = 0; ks < KCH; ++ks)
            #pragma unroll
            for (int F = 0; F < 4; ++F)
                Pu[F] = __builtin_amdgcn_mfma_f32_16x16x32_bf16(xlA[ks], wf[F][ks], Pu[F], 0, 0, 0);
        #pragma unroll
        for (int ks = 0; ks < KCH; ++ks)
            #pragma unroll
            for (int F = 0; F < 4; ++F)
                Pu[F] = __builtin_amdgcn_mfma_f32_16x16x32_bf16(xfA[ks], wfl[F][ks], Pu[F], 0, 0, 0);
    }
    #pragma unroll
    for (int F = 0; F < 4; ++F)
        #pragma unroll
        for (int r4 = 0; r4 < 4; ++r4)
            Pu[F][r4] += bgate[F];
    issue_x(1, xfB, xlB);

    float hsave[4];           // this lane's 4 owned steps per group (r = u&3)
    float creg = 0.f;

    // step-quarter base per lane's q: quarter order over time is q0,q1,q3,q2
    const int sbase = (q == 0) ? 0 : (q == 1) ? 4 : (q == 2) ? 12 : 8;

    // deferred h flush for group g (tail: only q<2 lanes = steps ..999)
    auto FLUSH = [&](int g, bool tail) {
        if (tail && q >= 2) return;
        const int s0 = g * 16 + sbase;
        const size_t col = (size_t)dir * HH + wv * 16 + j2;
        if (dir == 0) {
            __bf16* base = out + ((size_t)bb * T_ + s0) * 128 + col;
            #pragma unroll
            for (int r = 0; r < 4; ++r) base[r * 128] = (__bf16)hsave[r];
        } else {
            __bf16* base = out + ((size_t)bb * T_ + ((T_ - 1) - s0)) * 128 + col;
            #pragma unroll
            for (int r = 0; r < 4; ++r) *(base - r * 128) = (__bf16)hsave[r];
        }
        if constexpr (FIN) {
            if (!tail) {
                if (g == 0 && dir == 1 && q == 0)      // step s=0 -> t=999 (dir1)
                    outF[(size_t)bb * 128 + col] = hsave[0];
            } else {
                if (dir == 0 && q == 1)                // step s=999 (dir0)
                    outF[(size_t)bb * 128 + col] = hsave[3];
            }
        }
    };

    // one 16-step group; xcH/xcL = buffer holding x(grp+1) (consumed by Pn),
    // xnH/xnL = buffer to fill with x(grp+2) at u==0.
    auto GROUP = [&](int grp, auto& xcH, auto& xnH, auto& xcL, auto& xnL) {
        #pragma unroll
        for (int u = 0; u < 16; ++u) {
            // ds_reads first: broadcast h_{s-1} (all A-rows identical)
            bf16x8 ah0 = *(const bf16x8*)&hbuf[(u + 1) & 1][q * 8];
            bf16x8 ah1 = *(const bf16x8*)&hbuf[(u + 1) & 1][32 + q * 8];

            // ...deferred flush VALU+stores fill the ds latency at u==0
            if (u == 0 && grp > 0) FLUSH(grp - 1, false);

            // Pn pipeline: 1 MFMA/step (KCH=4: 16 over the group; L0: 12)
            if constexpr (!L0) {
                Pn[u & 3] = __builtin_amdgcn_mfma_f32_16x16x32_bf16(
                    xcH[u >> 2], wf[u & 3][u >> 2], Pn[u & 3], 0, 0, 0);
            } else {
                if (u < 4)
                    Pn[u] = __builtin_amdgcn_mfma_f32_16x16x32_bf16(xcH[0], wf[u][0], Pn[u], 0, 0, 0);
                else if (u < 8)
                    Pn[u - 4] = __builtin_amdgcn_mfma_f32_16x16x32_bf16(xcL[0], wf[u - 4][0], Pn[u - 4], 0, 0, 0);
                else if (u < 12)
                    Pn[u - 8] = __builtin_amdgcn_mfma_f32_16x16x32_bf16(xcH[0], wfl[u - 8][0], Pn[u - 8], 0, 0, 0);
            }

            // recurrent MFMAs: chained depth-2 (r20 proved the split hurts)
            f32x4 R[4];
            #pragma unroll
            for (int F = 0; F < 4; ++F) {
                f32x4 t = __builtin_amdgcn_mfma_f32_16x16x32_bf16(ah0, whf[F][0], Z4, 0, 0, 0);
                R[F] = __builtin_amdgcn_mfma_f32_16x16x32_bf16(ah1, whf[F][1], t, 0, 0, 0);
            }

            // x prefetch for grp+2 (fire-and-forget; consumed ~2 groups later)
            if (u == 0) issue_x(grp + 2, xnH, xnL);

            const int r = u & 3;
            const int qo = (u ^ ((u & 8) >> 1)) >> 2;   // owner quarter of step u
            float cold = creg;
            float iv = Pu[0][r] + R[0][r];   // bias pre-folded into Pu
            float fv = Pu[1][r] + R[1][r];
            float gv = Pu[2][r] + R[2][r];
            float ov = Pu[3][r] + R[3][r];
            float cn = fast_sigmoid(fv) * cold + fast_sigmoid(iv) * fast_tanh(gv);
            float hn = fast_sigmoid(ov) * fast_tanh(cn);
            // c-handoff to the next owner quarter: q0->q1 (u3, ^16), q1->q3
            // (u7, ^32), q3->q2 (u11, ^16), q2->q0-of-next-group (u15, ^32)
            if (u == 3 || u == 11)
                creg = __builtin_bit_cast(float,
                        __builtin_amdgcn_ds_swizzle(__builtin_bit_cast(int, cn), 0x401F));
            else if (u == 7 || u == 15)
                creg = __builtin_bit_cast(float,
                        __builtin_amdgcn_ds_bpermute(bpidx, __builtin_bit_cast(int, cn)));
            else
                creg = cn;
            if (q == qo) {
                hbuf[u & 1][wv * 16 + j2] = (__bf16)hn;
                hsave[r] = hn;
            }
            barrier_lds();
        }
        // rotate P for next group
        #pragma unroll
        for (int F = 0; F < 4; ++F) {
            Pu[F] = Pn[F];
            Pn[F] = Z4;
            #pragma unroll
            for (int r4 = 0; r4 < 4; ++r4) Pu[F][r4] += bgate[F];
        }
    };

    for (int g2 = 0; g2 < 31; ++g2) {
        GROUP(g2 * 2,     xfB, xfA, xlB, xlA);
        GROUP(g2 * 2 + 1, xfA, xfB, xlA, xlB);
    }
    GROUP(62, xfB, xfA, xlB, xlA);   // steps 992-1007; 1000+ computed, unstored
    FLUSH(62, true);
}

// ---------------------------------------------------------------- VALU fallback scan (r7-proven)
template<int KIN, typename TI, typename TO>
__global__ __launch_bounds__(256, 2) void scan_valu(
    const TI* __restrict__ in, const float* __restrict__ wih,
    const float* __restrict__ whh, const float* __restrict__ bias,
    TO* __restrict__ out)
{
    const int dir = blockIdx.y, bb = blockIdx.x, g = threadIdx.x;
    __shared__ __align__(16) float xs[8][KIN];
    __shared__ __align__(16) float act[256];
    __shared__ __align__(16) float hs[2][64];

    float wk[KIN], wr[64];
    {
        const float* wp = wih + (size_t)(dir * GG + g) * KIN;
        #pragma unroll
        for (int k4 = 0; k4 < KIN / 4; ++k4) {
            f32x4 v = *(const f32x4*)(wp + k4 * 4);
            wk[k4 * 4 + 0] = v.x; wk[k4 * 4 + 1] = v.y;
            wk[k4 * 4 + 2] = v.z; wk[k4 * 4 + 3] = v.w;
        }
        const float* rp = whh + (size_t)(dir * GG + g) * HH;
        #pragma unroll
        for (int j4 = 0; j4 < 16; ++j4) {
            f32x4 v = *(const f32x4*)(rp + j4 * 4);
            wr[j4 * 4 + 0] = v.x; wr[j4 * 4 + 1] = v.y;
            wr[j4 * 4 + 2] = v.z; wr[j4 * 4 + 3] = v.w;
        }
    }
    const float bg = bias[dir * GG + g];
    const bool is_g = (g >= 128 && g < 192);
    float c = 0.f;
    if (g < 64) hs[0][g] = 0.f;
    __syncthreads();

    float hreg[8];
    for (int ch = 0; ch < 125; ++ch) {
        if constexpr (KIN == 128) {
            int l = g * 4, u = l >> 7, k = l & 127;
            int s = ch * 8 + u, tt = dir ? (T_ - 1) - s : s;
            const TI* src = in + ((size_t)bb * T_ + tt) * 128 + k;
            f32x4 fv;
            if constexpr (std::is_same_v<TI, float>) fv = *(const f32x4*)src;
            else {
                ushort4 rv = *(const ushort4*)src;
                fv = (f32x4){bf2f(rv.x), bf2f(rv.y), bf2f(rv.z), bf2f(rv.w)};
            }
            *(f32x4*)&xs[u][k] = fv;
        } else {
            int u = g >> 5, k = g & 31;
            int s = ch * 8 + u, tt = dir ? (T_ - 1) - s : s;
            if constexpr (std::is_same_v<TI, float>)
                xs[u][k] = in[((size_t)bb * T_ + tt) * 32 + k];
            else
                xs[u][k] = bf2f(((const unsigned short*)in)[((size_t)bb * T_ + tt) * 32 + k]);
        }
        __syncthreads();
        #pragma unroll
        for (int u = 0; u < 8; ++u) {
            const int p = (ch * 8 + u) & 1;
            float a0 = bg, a1 = 0.f, a2 = 0.f, a3 = 0.f;
            #pragma unroll
            for (int k = 0; k < KIN; k += 4) {
                f32x4 xv = *(const f32x4*)&xs[u][k];
                a0 = fmaf(xv.x, wk[k + 0], a0); a1 = fmaf(xv.y, wk[k + 1], a1);
                a2 = fmaf(xv.z, wk[k + 2], a2); a3 = fmaf(xv.w, wk[k + 3], a3);
            }
            #pragma unroll
            for (int j = 0; j < 64; j += 4) {
                f32x4 hv = *(const f32x4*)&hs[p][j];
                a0 = fmaf(hv.x, wr[j + 0], a0); a1 = fmaf(hv.y, wr[j + 1], a1);
                a2 = fmaf(hv.z, wr[j + 2], a2); a3 = fmaf(hv.w, wr[j + 3], a3);
            }
            float a = (a0 + a1) + (a2 + a3);
            act[g] = is_g ? fast_tanh(a) : fast_sigmoid(a);
            __syncthreads();
            if (g < 64) {
                float iv = act[g], fv = act[64 + g], gv = act[128 + g], ov = act[192 + g];
                c = fmaf(fv, c, iv * gv);
                float hn = ov * fast_tanh(c);
                hs[p ^ 1][g] = hn;
                hreg[u] = hn;
            }
            __syncthreads();
        }
        if (g < 64) {
            #pragma unroll
            for (int u = 0; u < 8; ++u) {
                int s = ch * 8 + u, tt = dir ? (T_ - 1) - s : s;
                out[((size_t)bb * T_ + tt) * 128 + dir * HH + g] = (TO)hreg[u];
            }
        }
    }
}

// ---------------------------------------------------------------- heads (f32 out)
__global__ __launch_bounds__(64) void head_last(
    const float* __restrict__ hl, const float* __restrict__ wlin,
    const float* __restrict__ blin, float* __restrict__ outp) {
    const int b = blockIdx.x, tid = threadIdx.x;
    __shared__ float hv[128];
    hv[tid] = hl[(size_t)b * 128 + tid];
    hv[64 + tid] = hl[(size_t)b * 128 + 64 + tid];
    __syncthreads();
    if (tid < 54) {
        float a = blin[tid];
        #pragma unroll 4
        for (int j = 0; j < 128; ++j) a = fmaf(hv[j], wlin[tid * 128 + j], a);
        outp[b * 54 + tid] = a;
    }
}

template<typename TI>
__global__ __launch_bounds__(64) void head_kernel(
    const TI* __restrict__ fin, const float* __restrict__ wlin,
    const float* __restrict__ blin, float* __restrict__ outp) {
    const int b = blockIdx.x, tid = threadIdx.x;
    __shared__ float hv[128];
    #pragma unroll
    for (int rr = 0; rr < 2; ++rr) {
        int j = rr * 64 + tid;
        hv[j] = (float)fin[((size_t)b * T_ + (T_ - 1)) * 128 + j];
    }
    __syncthreads();
    if (tid < 54) {
        float a = blin[tid];
        #pragma unroll 4
        for (int j = 0; j < 128; ++j) a = fmaf(hv[j], wlin[tid * 128 + j], a);
        outp[b * 54 + tid] = a;
    }
}

extern "C" void kernel_launch(void* const* d_in, const int* in_sizes, int n_in,
                              void* d_out, int out_size, void* d_ws, size_t ws_size,
                              hipStream_t stream) {
    const float* x    = (const float*)d_in[0];
    const float* wihf = (const float*)d_in[1];
    const float* wihr = (const float*)d_in[2];
    const float* whh  = (const float*)d_in[3];
    const float* bih  = (const float*)d_in[4];
    const float* bhh  = (const float*)d_in[5];
    const float* wlin = (const float*)d_in[6];
    const float* blin = (const float*)d_in[7];
    float* outp = (float*)d_out;

    char* ws = (char*)d_ws;
    const size_t PB = (size_t)NB * T_ * 128 * sizeof(__bf16);  // 65,536,000
    const size_t PX = (size_t)NB * T_ * 32 * sizeof(__bf16);   // 16,384,000
    const size_t HL = (size_t)NB * 128 * sizeof(float);        //    131,072
    const size_t WSZ = 794624;
    const bool primary = ws_size >= 2 * PB + 2 * PX + HL + WSZ;  // ~164.8 MB (proven >=263)

    char* sw = primary ? (ws + 2 * PB + 2 * PX + HL) : (ws + 2 * PB);
    __bf16* w0H  = (__bf16*)(sw);             //  32,768 B
    __bf16* w0L  = (__bf16*)(sw + 32768);     //  32,768 B
    __bf16* wrH  = (__bf16*)(sw + 65536);     // 393,216 B
    __bf16* whH  = (__bf16*)(sw + 458752);    // 262,144 B
    float*  bias = (float*) (sw + 720896);    //   8,192 B
    float*  w0f  = (float*) (sw + 729088);    //  65,536 B (VALU fallback)

    prep_w<<<768, 256, 0, stream>>>(wihf, wihr, whh, bih, bhh,
                                    w0H, w0L, wrH, whH, bias, w0f);

    if (primary) {
        __bf16* A   = (__bf16*)ws;
        __bf16* B   = (__bf16*)(ws + PB);
        __bf16* xhi = (__bf16*)(ws + 2 * PB);
        __bf16* xlo = (__bf16*)(ws + 2 * PB + PX);
        float*  hl  = (float*)(ws + 2 * PB + 2 * PX);
        prep_x_ps<<<NB, 256, 0, stream>>>(x, xhi, xlo);
        const dim3 sgrid(NB, 2);   // 512 blocks: 1 chain each, 2 blocks/CU
        fused_scan1c<1, true,  false><<<sgrid, 256, 0, stream>>>(xhi, xlo, w0H, w0L, whH, bias, A, nullptr);
        fused_scan1c<4, false, false><<<sgrid, 256, 0, stream>>>(A, nullptr, wrH, nullptr,
            whH + 32768, bias + 512, B, nullptr);
        fused_scan1c<4, false, false><<<sgrid, 256, 0, stream>>>(B, nullptr, wrH + 65536, nullptr,
            whH + 65536, bias + 1024, A, nullptr);
        fused_scan1c<4, false, true><<<sgrid, 256, 0, stream>>>(A, nullptr, wrH + 131072, nullptr,
            whH + 98304, bias + 1536, B, hl);
        head_last<<<NB, 64, 0, stream>>>(hl, wlin, blin, outp);
    } else {
        __bf16* A = (__bf16*)ws;
        __bf16* B = (__bf16*)(ws + PB);
        __bf16* xp = (__bf16*)ws;  // aliases A; dead before A written
        prep_x_b<<<NB, 256, 0, stream>>>(x, xp);
        const dim3 vgrid(NB, 2);
        scan_valu<32, __bf16, __bf16><<<vgrid, 256, 0, stream>>>(xp, w0f, whh, bias, B);
        scan_valu<128, __bf16, __bf16><<<vgrid, 256, 0, stream>>>(B, wihr,          whh + 32768, bias + 512,  A);
        scan_valu<128, __bf16, __bf16><<<vgrid, 256, 0, stream>>>(A, wihr + 65536,  whh + 65536, bias + 1024, B);
        scan_valu<128, __bf16, __bf16><<<vgrid, 256, 0, stream>>>(B, wihr + 131072, whh + 98304, bias + 1536, A);
        head_kernel<__bf16><<<NB, 64, 0, stream>>>(A, wlin, blin, outp);
    }
}

// Round 9
// 1296.246 us; speedup vs baseline: 1.0870x; 1.0870x over previous
//
#include <hip/hip_runtime.h>
#include <hip/hip_bf16.h>
#include <type_traits>

#define T_    1000
#define NB    256
#define HH    64
#define GG    256

typedef float f32x4 __attribute__((ext_vector_type(4)));
typedef __bf16 bf16x8 __attribute__((ext_vector_type(8)));

// Barrier that does NOT drain vmcnt (plain __syncthreads emits s_waitcnt vmcnt(0)
// which would stall on global h-stores and x-prefetch every step).
__device__ __forceinline__ void barrier_lds() {
    asm volatile("s_waitcnt lgkmcnt(0)\n\ts_barrier" ::: "memory");
}

__device__ __forceinline__ float fast_sigmoid(float x) {
    float e = __expf(-x);
    return __builtin_amdgcn_rcpf(1.f + e);
}
__device__ __forceinline__ float fast_tanh(float x) {
    x = fmaxf(x, -15.f);
    float e = __expf(-2.f * x);
    return (1.f - e) * __builtin_amdgcn_rcpf(1.f + e);
}
__device__ __forceinline__ float bf2f(unsigned short u) {
    return __builtin_bit_cast(float, (unsigned)u << 16);
}

// ---------------------------------------------------------------- weight prep
__global__ void prep_w(const float* __restrict__ wihf, const float* __restrict__ wihr,
                       const float* __restrict__ whh, const float* __restrict__ bih,
                       const float* __restrict__ bhh,
                       __bf16* __restrict__ w0H, __bf16* __restrict__ w0L,
                       __bf16* __restrict__ wrH, __bf16* __restrict__ whH,
                       float* __restrict__ bias, float* __restrict__ w0f) {
    int i = blockIdx.x * 256 + threadIdx.x;
    if (i < 2 * GG * 32) {
        int k = i & 31, gd = i >> 5;
        float w = (k < 22) ? wihf[gd * 22 + k] : 0.f;
        __bf16 h = (__bf16)w;
        w0H[i] = h; w0L[i] = (__bf16)(w - (float)h);
        w0f[i] = w;
    }
    if (i < 3 * 2 * GG * 128) wrH[i] = (__bf16)wihr[i];
    if (i < 4 * 2 * GG * HH)  whH[i] = (__bf16)whh[i];
    if (i < 4 * 2 * GG)       bias[i] = bih[i] + bhh[i];
}

// ---------------------------------------------------------------- x prep, hi/lo bf16 planes (layer 0)
__global__ __launch_bounds__(256) void prep_x_ps(const float* __restrict__ x,
                                                 __bf16* __restrict__ xhi,
                                                 __bf16* __restrict__ xlo) {
    const int b = blockIdx.x;
    __shared__ float xs[22][104];
    for (int tc = 0; tc < 10; ++tc) {
        const int t0 = tc * 100;
        __syncthreads();
        for (int i = threadIdx.x; i < 22 * 100; i += 256) {
            int k = i / 100, t = i - k * 100;
            xs[k][t] = x[((size_t)b * 22 + k) * T_ + t0 + t];
        }
        __syncthreads();
        for (int i = threadIdx.x; i < 100 * 4; i += 256) {
            int t = i >> 2, p = i & 3;
            bf16x8 vh, vl;
            #pragma unroll
            for (int j = 0; j < 8; ++j) {
                int k = p * 8 + j;
                float f = (k < 22) ? xs[k][t] : 0.f;
                __bf16 h = (__bf16)f;
                vh[j] = h;
                vl[j] = (__bf16)(f - (float)h);
            }
            *(bf16x8*)(xhi + ((size_t)b * T_ + t0 + t) * 32 + p * 8) = vh;
            *(bf16x8*)(xlo + ((size_t)b * T_ + t0 + t) * 32 + p * 8) = vl;
        }
    }
}

// ---------------------------------------------------------------- x prep single bf16 plane (fallback)
__global__ __launch_bounds__(256) void prep_x_b(const float* __restrict__ x,
                                                __bf16* __restrict__ xp) {
    const int b = blockIdx.x;
    __shared__ float xs[22][104];
    for (int tc = 0; tc < 10; ++tc) {
        const int t0 = tc * 100;
        __syncthreads();
        for (int i = threadIdx.x; i < 22 * 100; i += 256) {
            int k = i / 100, t = i - k * 100;
            xs[k][t] = x[((size_t)b * 22 + k) * T_ + t0 + t];
        }
        __syncthreads();
        for (int i = threadIdx.x; i < 100 * 4; i += 256) {
            int t = i >> 2, p = i & 3;
            bf16x8 v;
            #pragma unroll
            for (int j = 0; j < 8; ++j) {
                int k = p * 8 + j;
                v[j] = (k < 22) ? (__bf16)xs[k][t] : (__bf16)0.f;
            }
            *(bf16x8*)(xp + ((size_t)b * T_ + t0 + t) * 32 + p * 8) = v;
        }
    }
}

// ---------------------------------------------------------------- MFMA fused layer, 2 chains/block (r13 shape)
// r22 = r15 base (304us/layer verified; weights in regs, ds_swizzle 0x401F
// c-exchange, r15 labels) + three shadow-filling / junction edits:
//  (1) FLUSH spread 1 store/step (hsA/hsB ping-pong): every step's post-barrier
//      ds_read shadow now holds a global store + addr VALU (r15 clumped all 8
//      at u==0, leaving 7 steps with only 2 Pn-MFMAs against ~120cy LDS lat).
//  (2) issue_x spread at u==1,2 (2 loads each; L0 at u==1) - declumps u==0.
//  (3) Pu folded into R-MFMA C-in: R=mfma(ah1,whf1,mfma(ah0,whf0,Pu[F]));
//      gates = R[F][r] directly (kills 4 extracts + 4 adds at the serial
//      MFMA->act junction). Sound per D-layout: rows within a chain identical,
//      so owner lane's element r=u&3 is R_chain + P[step u].
// Kept OUT (failed variants): LDS weight streaming (r16), bias-splat residency
// + lambda-ref P rotation (r17), permlane c-exchange (r18/r19), R depth-1
// split (r20), occupancy doubling (r14/r21 - wall time = 1000 x step latency;
// co-residency only adds issue contention).
template<int KCH, bool L0, bool FIN>
__global__ __launch_bounds__(256, 1) void fused_scan3(
    const __bf16* __restrict__ inA,   // (B,T,KCH*32) bf16 (hi plane if L0)
    const __bf16* __restrict__ inB,   // lo plane (iff L0)
    const __bf16* __restrict__ wihH,  // (2,256,KCH*32) bf16 hi
    const __bf16* __restrict__ wihL,  // same, lo (iff L0)
    const __bf16* __restrict__ whhH,  // (2,256,64) bf16
    const float*  __restrict__ bias,  // (2,256) f32
    __bf16* __restrict__ out,         // (B,T,128) bf16
    float* __restrict__ outF)         // (B,128) f32 last-t h (iff FIN)
{
    const int dir = blockIdx.y;
    const int b0 = blockIdx.x * 2;
    const int tid = threadIdx.x;
    const int wv = tid >> 6, lane = tid & 63;
    const int j2 = lane & 15, q = lane >> 4;
    const int ch_l = j2 >> 3;          // chain of this lane's A-row
    const int u_l = j2 & 7;            // step-in-group of this lane's A-row
    constexpr int KIN = KCH * 32;

    __shared__ __align__(16) __bf16 hbuf[2][2][80]; // [parity][chain][j pad]

    const f32x4 Z4 = (f32x4){0.f, 0.f, 0.f, 0.f};

    bf16x8 wf[4][KCH], wfl[4][L0 ? KCH : 1];
    bf16x8 whf[4][2];
    float bgate[4];
    #pragma unroll
    for (int F = 0; F < 4; ++F) {
        const int g = (F * 4 + wv) * 16 + j2;
        bgate[F] = bias[dir * GG + g];
        #pragma unroll
        for (int ks = 0; ks < KCH; ++ks) {
            wf[F][ks] = *(const bf16x8*)(wihH + ((size_t)dir * GG + g) * KIN + ks * 32 + q * 8);
            if constexpr (L0)
                wfl[F][ks] = *(const bf16x8*)(wihL + ((size_t)dir * GG + g) * KIN + ks * 32 + q * 8);
        }
        #pragma unroll
        for (int ks = 0; ks < 2; ++ks)
            whf[F][ks] = *(const bf16x8*)(whhH + ((size_t)dir * GG + g) * HH + ks * 32 + q * 8);
    }
    if (tid < 64) {
        hbuf[1][0][tid] = (__bf16)0.f;
        hbuf[1][1][tid] = (__bf16)0.f;
    }
    __syncthreads();

    // double-buffered x fragments: A holds even-group x, B holds odd-group x
    bf16x8 xfA[KCH], xfB[KCH];
    bf16x8 xlA[L0 ? KCH : 1], xlB[L0 ? KCH : 1];
    auto issue_x = [&](int grp, auto& dh, auto& dl) {
        int s = grp * 8 + u_l;
        if (s > T_ - 1) s = T_ - 1;
        int tt = dir ? (T_ - 1) - s : s;
        const __bf16* ph = inA + ((size_t)(b0 + ch_l) * T_ + tt) * KIN + q * 8;
        #pragma unroll
        for (int ks = 0; ks < KCH; ++ks)
            dh[ks] = *(const bf16x8*)(ph + ks * 32);
        if constexpr (L0) {
            const __bf16* pl = inB + ((size_t)(b0 + ch_l) * T_ + tt) * KIN + q * 8;
            #pragma unroll
            for (int ks = 0; ks < KCH; ++ks)
                dl[ks] = *(const bf16x8*)(pl + ks * 32);
        }
    };
    // half-spread variant: load 2 of the 4 ks chunks (KCH=4 path)
    auto issue_x_half = [&](int grp, auto& dh, int half) {
        int s = grp * 8 + u_l;
        if (s > T_ - 1) s = T_ - 1;
        int tt = dir ? (T_ - 1) - s : s;
        const __bf16* ph = inA + ((size_t)(b0 + ch_l) * T_ + tt) * KIN + q * 8;
        #pragma unroll
        for (int ks = 0; ks < 2; ++ks)
            dh[half * 2 + ks] = *(const bf16x8*)(ph + (half * 2 + ks) * 32);
    };

    // ---- prologue: P for group 0 (+bias), then prefetch group 1
    f32x4 Pu[4], Pn[4];
    #pragma unroll
    for (int F = 0; F < 4; ++F) { Pu[F] = Z4; Pn[F] = Z4; }
    issue_x(0, xfA, xlA);
    #pragma unroll
    for (int ks = 0; ks < KCH; ++ks)
        #pragma unroll
        for (int F = 0; F < 4; ++F)
            Pu[F] = __builtin_amdgcn_mfma_f32_16x16x32_bf16(xfA[ks], wf[F][ks], Pu[F], 0, 0, 0);
    if constexpr (L0) {
        #pragma unroll
        for (int ks = 0; ks < KCH; ++ks)
            #pragma unroll
            for (int F = 0; F < 4; ++F)
                Pu[F] = __builtin_amdgcn_mfma_f32_16x16x32_bf16(xlA[ks], wf[F][ks], Pu[F], 0, 0, 0);
        #pragma unroll
        for (int ks = 0; ks < KCH; ++ks)
            #pragma unroll
            for (int F = 0; F < 4; ++F)
                Pu[F] = __builtin_amdgcn_mfma_f32_16x16x32_bf16(xfA[ks], wfl[F][ks], Pu[F], 0, 0, 0);
    }
    #pragma unroll
    for (int F = 0; F < 4; ++F)
        #pragma unroll
        for (int r4 = 0; r4 < 4; ++r4)
            Pu[F][r4] += bgate[F];
    issue_x(1, xfB, xlB);

    float hsA[8], hsB[8];
    float creg = 0.f;

    // clumped flush (epilogue only): 8 bf16 stores with compile-time offsets
    auto FLUSH = [&](int g, float (&hs)[8]) {
        const int ch = q >> 1;
        const size_t col = (size_t)dir * HH + wv * 16 + j2;
        if (dir == 0) {
            __bf16* base = out + ((size_t)(b0 + ch) * T_ + g * 8) * 128 + col;
            #pragma unroll
            for (int u = 0; u < 8; ++u)
                if ((q & 1) == (u >> 2)) base[u * 128] = (__bf16)hs[u];
            if constexpr (FIN)
                if (g == 124 && (q & 1) == 1)
                    outF[(size_t)(b0 + ch) * 128 + col] = hs[7];
        } else {
            __bf16* base = out + ((size_t)(b0 + ch) * T_ + ((T_ - 1) - g * 8)) * 128 + col;
            #pragma unroll
            for (int u = 0; u < 8; ++u)
                if ((q & 1) == (u >> 2)) *(base - u * 128) = (__bf16)hs[u];
            if constexpr (FIN)
                if (g == 0 && (q & 1) == 0)
                    outF[(size_t)(b0 + ch) * 128 + col] = hs[0];
        }
    };

    // one 8-step group; xc = x(grp+1) (feeds Pn), xn = buffer for x(grp+2).
    // hsC = this group's h regs; hsP = previous group's, flushed 1 store/step.
    auto GROUP = [&](int grp, auto& xcH, auto& xnH, auto& xcL, auto& xnL,
                     float (&hsC)[8], float (&hsP)[8]) {
        const bool doflush = grp > 0;
        const int gprev = doflush ? grp - 1 : 0;
        const int ch = q >> 1;
        const ptrdiff_t fstep = dir ? -128 : 128;
        const int bt = dir ? (T_ - 1) - gprev * 8 : gprev * 8;
        __bf16* fb = out + ((size_t)(b0 + ch) * T_ + bt) * 128
                         + (size_t)dir * HH + wv * 16 + j2;
        #pragma unroll
        for (int u = 0; u < 8; ++u) {
            const int rp = (u + 1) & 1;   // grp*8 even -> parity compile-time
            // ds_reads first...
            bf16x8 ah0 = *(const bf16x8*)&hbuf[rp][ch_l][q * 8];
            bf16x8 ah1 = *(const bf16x8*)&hbuf[rp][ch_l][32 + q * 8];

            // spread flush: one store of prev group's h per step (owner mask
            // for step u matches hsP's writer mask)
            if (doflush && ((q & 1) == (u >> 2))) {
                fb[(ptrdiff_t)u * fstep] = (__bf16)hsP[u];
                if constexpr (FIN)
                    if (dir == 1 && grp == 1 && u == 0)
                        outF[(size_t)(b0 + ch) * 128 + HH + wv * 16 + j2] = hsP[0];
            }

            // spread x prefetch for grp+2
            if constexpr (L0) {
                if (u == 1) issue_x(grp + 2, xnH, xnL);
            } else {
                if (u == 1) issue_x_half(grp + 2, xnH, 0);
                if (u == 2) issue_x_half(grp + 2, xnH, 1);
            }

            // Pn pipeline (independent -> fills ds latency)
            if constexpr (!L0) {
                const int ks = u >> 1;
                const int Fb = (u & 1) * 2;
                Pn[Fb]     = __builtin_amdgcn_mfma_f32_16x16x32_bf16(xcH[ks], wf[Fb][ks],     Pn[Fb], 0, 0, 0);
                Pn[Fb + 1] = __builtin_amdgcn_mfma_f32_16x16x32_bf16(xcH[ks], wf[Fb + 1][ks], Pn[Fb + 1], 0, 0, 0);
            } else {
                if (u == 0) {
                    #pragma unroll
                    for (int F = 0; F < 4; ++F)
                        Pn[F] = __builtin_amdgcn_mfma_f32_16x16x32_bf16(xcH[0], wf[F][0], Pn[F], 0, 0, 0);
                } else if (u == 1) {
                    #pragma unroll
                    for (int F = 0; F < 4; ++F)
                        Pn[F] = __builtin_amdgcn_mfma_f32_16x16x32_bf16(xcL[0], wf[F][0], Pn[F], 0, 0, 0);
                } else if (u == 2) {
                    #pragma unroll
                    for (int F = 0; F < 4; ++F)
                        Pn[F] = __builtin_amdgcn_mfma_f32_16x16x32_bf16(xcH[0], wfl[F][0], Pn[F], 0, 0, 0);
                }
            }

            // recurrent MFMAs with P(+bias) as C-in: gates = R[F][r] directly
            f32x4 R[4];
            #pragma unroll
            for (int F = 0; F < 4; ++F) {
                f32x4 t = __builtin_amdgcn_mfma_f32_16x16x32_bf16(ah0, whf[F][0], Pu[F], 0, 0, 0);
                R[F] = __builtin_amdgcn_mfma_f32_16x16x32_bf16(ah1, whf[F][1], t, 0, 0, 0);
            }

            const int r = u & 3;
            float cold = creg;
            float iv = R[0][r];
            float fv = R[1][r];
            float gv = R[2][r];
            float ov = R[3][r];
            float cn = fast_sigmoid(fv) * cold + fast_sigmoid(iv) * fast_tanh(gv);
            float hn = fast_sigmoid(ov) * fast_tanh(cn);
            // c-handoff between q-lane-halves via lane^16 swizzle (r15-proven)
            if (u == 3 || u == 7)
                creg = __builtin_bit_cast(float,
                        __builtin_amdgcn_ds_swizzle(__builtin_bit_cast(int, cn), 0x401F));
            else
                creg = cn;
            const bool owner = ((q & 1) == (u >> 2));
            if (owner) {
                hbuf[u & 1][ch][wv * 16 + j2] = (__bf16)hn;
                hsC[u] = hn;
            }
            barrier_lds();
        }
        // rotate P for next group (bias re-folded)
        #pragma unroll
        for (int F = 0; F < 4; ++F) {
            Pu[F] = Pn[F];
            Pn[F] = Z4;
            #pragma unroll
            for (int r4 = 0; r4 < 4; ++r4) Pu[F][r4] += bgate[F];
        }
    };

    for (int g2 = 0; g2 < 62; ++g2) {
        GROUP(g2 * 2,     xfB, xfA, xlB, xlA, hsA, hsB);
        GROUP(g2 * 2 + 1, xfA, xfB, xlA, xlB, hsB, hsA);
    }
    GROUP(124, xfB, xfA, xlB, xlA, hsA, hsB);
    FLUSH(124, hsA);
}

// ---------------------------------------------------------------- VALU fallback scan (r7-proven)
template<int KIN, typename TI, typename TO>
__global__ __launch_bounds__(256, 2) void scan_valu(
    const TI* __restrict__ in, const float* __restrict__ wih,
    const float* __restrict__ whh, const float* __restrict__ bias,
    TO* __restrict__ out)
{
    const int dir = blockIdx.y, bb = blockIdx.x, g = threadIdx.x;
    __shared__ __align__(16) float xs[8][KIN];
    __shared__ __align__(16) float act[256];
    __shared__ __align__(16) float hs[2][64];

    float wk[KIN], wr[64];
    {
        const float* wp = wih + (size_t)(dir * GG + g) * KIN;
        #pragma unroll
        for (int k4 = 0; k4 < KIN / 4; ++k4) {
            f32x4 v = *(const f32x4*)(wp + k4 * 4);
            wk[k4 * 4 + 0] = v.x; wk[k4 * 4 + 1] = v.y;
            wk[k4 * 4 + 2] = v.z; wk[k4 * 4 + 3] = v.w;
        }
        const float* rp = whh + (size_t)(dir * GG + g) * HH;
        #pragma unroll
        for (int j4 = 0; j4 < 16; ++j4) {
            f32x4 v = *(const f32x4*)(rp + j4 * 4);
            wr[j4 * 4 + 0] = v.x; wr[j4 * 4 + 1] = v.y;
            wr[j4 * 4 + 2] = v.z; wr[j4 * 4 + 3] = v.w;
        }
    }
    const float bg = bias[dir * GG + g];
    const bool is_g = (g >= 128 && g < 192);
    float c = 0.f;
    if (g < 64) hs[0][g] = 0.f;
    __syncthreads();

    float hreg[8];
    for (int ch = 0; ch < 125; ++ch) {
        if constexpr (KIN == 128) {
            int l = g * 4, u = l >> 7, k = l & 127;
            int s = ch * 8 + u, tt = dir ? (T_ - 1) - s : s;
            const TI* src = in + ((size_t)bb * T_ + tt) * 128 + k;
            f32x4 fv;
            if constexpr (std::is_same_v<TI, float>) fv = *(const f32x4*)src;
            else {
                ushort4 rv = *(const ushort4*)src;
                fv = (f32x4){bf2f(rv.x), bf2f(rv.y), bf2f(rv.z), bf2f(rv.w)};
            }
            *(f32x4*)&xs[u][k] = fv;
        } else {
            int u = g >> 5, k = g & 31;
            int s = ch * 8 + u, tt = dir ? (T_ - 1) - s : s;
            if constexpr (std::is_same_v<TI, float>)
                xs[u][k] = in[((size_t)bb * T_ + tt) * 32 + k];
            else
                xs[u][k] = bf2f(((const unsigned short*)in)[((size_t)bb * T_ + tt) * 32 + k]);
        }
        __syncthreads();
        #pragma unroll
        for (int u = 0; u < 8; ++u) {
            const int p = (ch * 8 + u) & 1;
            float a0 = bg, a1 = 0.f, a2 = 0.f, a3 = 0.f;
            #pragma unroll
            for (int k = 0; k < KIN; k += 4) {
                f32x4 xv = *(const f32x4*)&xs[u][k];
                a0 = fmaf(xv.x, wk[k + 0], a0); a1 = fmaf(xv.y, wk[k + 1], a1);
                a2 = fmaf(xv.z, wk[k + 2], a2); a3 = fmaf(xv.w, wk[k + 3], a3);
            }
            #pragma unroll
            for (int j = 0; j < 64; j += 4) {
                f32x4 hv = *(const f32x4*)&hs[p][j];
                a0 = fmaf(hv.x, wr[j + 0], a0); a1 = fmaf(hv.y, wr[j + 1], a1);
                a2 = fmaf(hv.z, wr[j + 2], a2); a3 = fmaf(hv.w, wr[j + 3], a3);
            }
            float a = (a0 + a1) + (a2 + a3);
            act[g] = is_g ? fast_tanh(a) : fast_sigmoid(a);
            __syncthreads();
            if (g < 64) {
                float iv = act[g], fv = act[64 + g], gv = act[128 + g], ov = act[192 + g];
                c = fmaf(fv, c, iv * gv);
                float hn = ov * fast_tanh(c);
                hs[p ^ 1][g] = hn;
                hreg[u] = hn;
            }
            __syncthreads();
        }
        if (g < 64) {
            #pragma unroll
            for (int u = 0; u < 8; ++u) {
                int s = ch * 8 + u, tt = dir ? (T_ - 1) - s : s;
                out[((size_t)bb * T_ + tt) * 128 + dir * HH + g] = (TO)hreg[u];
            }
        }
    }
}

// ---------------------------------------------------------------- heads (f32 out)
__global__ __launch_bounds__(64) void head_last(
    const float* __restrict__ hl, const float* __restrict__ wlin,
    const float* __restrict__ blin, float* __restrict__ outp) {
    const int b = blockIdx.x, tid = threadIdx.x;
    __shared__ float hv[128];
    hv[tid] = hl[(size_t)b * 128 + tid];
    hv[64 + tid] = hl[(size_t)b * 128 + 64 + tid];
    __syncthreads();
    if (tid < 54) {
        float a = blin[tid];
        #pragma unroll 4
        for (int j = 0; j < 128; ++j) a = fmaf(hv[j], wlin[tid * 128 + j], a);
        outp[b * 54 + tid] = a;
    }
}

template<typename TI>
__global__ __launch_bounds__(64) void head_kernel(
    const TI* __restrict__ fin, const float* __restrict__ wlin,
    const float* __restrict__ blin, float* __restrict__ outp) {
    const int b = blockIdx.x, tid = threadIdx.x;
    __shared__ float hv[128];
    #pragma unroll
    for (int rr = 0; rr < 2; ++rr) {
        int j = rr * 64 + tid;
        hv[j] = (float)fin[((size_t)b * T_ + (T_ - 1)) * 128 + j];
    }
    __syncthreads();
    if (tid < 54) {
        float a = blin[tid];
        #pragma unroll 4
        for (int j = 0; j < 128; ++j) a = fmaf(hv[j], wlin[tid * 128 + j], a);
        outp[b * 54 + tid] = a;
    }
}

extern "C" void kernel_launch(void* const* d_in, const int* in_sizes, int n_in,
                              void* d_out, int out_size, void* d_ws, size_t ws_size,
                              hipStream_t stream) {
    const float* x    = (const float*)d_in[0];
    const float* wihf = (const float*)d_in[1];
    const float* wihr = (const float*)d_in[2];
    const float* whh  = (const float*)d_in[3];
    const float* bih  = (const float*)d_in[4];
    const float* bhh  = (const float*)d_in[5];
    const float* wlin = (const float*)d_in[6];
    const float* blin = (const float*)d_in[7];
    float* outp = (float*)d_out;

    char* ws = (char*)d_ws;
    const size_t PB = (size_t)NB * T_ * 128 * sizeof(__bf16);  // 65,536,000
    const size_t PX = (size_t)NB * T_ * 32 * sizeof(__bf16);   // 16,384,000
    const size_t HL = (size_t)NB * 128 * sizeof(float);        //    131,072
    const size_t WSZ = 794624;
    const bool primary = ws_size >= 2 * PB + 2 * PX + HL + WSZ;  // ~164.8 MB (proven >=263)

    char* sw = primary ? (ws + 2 * PB + 2 * PX + HL) : (ws + 2 * PB);
    __bf16* w0H  = (__bf16*)(sw);             //  32,768 B
    __bf16* w0L  = (__bf16*)(sw + 32768);     //  32,768 B
    __bf16* wrH  = (__bf16*)(sw + 65536);     // 393,216 B
    __bf16* whH  = (__bf16*)(sw + 458752);    // 262,144 B
    float*  bias = (float*) (sw + 720896);    //   8,192 B
    float*  w0f  = (float*) (sw + 729088);    //  65,536 B (VALU fallback)

    prep_w<<<768, 256, 0, stream>>>(wihf, wihr, whh, bih, bhh,
                                    w0H, w0L, wrH, whH, bias, w0f);

    if (primary) {
        __bf16* A   = (__bf16*)ws;
        __bf16* B   = (__bf16*)(ws + PB);
        __bf16* xhi = (__bf16*)(ws + 2 * PB);
        __bf16* xlo = (__bf16*)(ws + 2 * PB + PX);
        float*  hl  = (float*)(ws + 2 * PB + 2 * PX);
        prep_x_ps<<<NB, 256, 0, stream>>>(x, xhi, xlo);
        const dim3 sgrid(NB / 2, 2);
        fused_scan3<1, true,  false><<<sgrid, 256, 0, stream>>>(xhi, xlo, w0H, w0L, whH, bias, A, nullptr);
        fused_scan3<4, false, false><<<sgrid, 256, 0, stream>>>(A, nullptr, wrH, nullptr,
            whH + 32768, bias + 512, B, nullptr);
        fused_scan3<4, false, false><<<sgrid, 256, 0, stream>>>(B, nullptr, wrH + 65536, nullptr,
            whH + 65536, bias + 1024, A, nullptr);
        fused_scan3<4, false, true><<<sgrid, 256, 0, stream>>>(A, nullptr, wrH + 131072, nullptr,
            whH + 98304, bias + 1536, B, hl);
        head_last<<<NB, 64, 0, stream>>>(hl, wlin, blin, outp);
    } else {
        __bf16* A = (__bf16*)ws;
        __bf16* B = (__bf16*)(ws + PB);
        __bf16* xp = (__bf16*)ws;  // aliases A; dead before A written
        prep_x_b<<<NB, 256, 0, stream>>>(x, xp);
        const dim3 vgrid(NB, 2);
        scan_valu<32, __bf16, __bf16><<<vgrid, 256, 0, stream>>>(xp, w0f, whh, bias, B);
        scan_valu<128, __bf16, __bf16><<<vgrid, 256, 0, stream>>>(B, wihr,          whh + 32768, bias + 512,  A);
        scan_valu<128, __bf16, __bf16><<<vgrid, 256, 0, stream>>>(A, wihr + 65536,  whh + 65536, bias + 1024, B);
        scan_valu<128, __bf16, __bf16><<<vgrid, 256, 0, stream>>>(B, wihr + 131072, whh + 98304, bias + 1536, A);
        head_kernel<__bf16><<<NB, 64, 0, stream>>>(A, wlin, blin, outp);
    }
}

// Round 11
// 1179.448 us; speedup vs baseline: 1.1946x; 1.0990x over previous
//
#include <hip/hip_runtime.h>
#include <hip/hip_bf16.h>
#include <type_traits>

#define T_    1000
#define NB    256
#define HH    64
#define GG    256

typedef float f32x4 __attribute__((ext_vector_type(4)));
typedef __bf16 bf16x8 __attribute__((ext_vector_type(8)));

// Barrier that does NOT drain vmcnt (plain __syncthreads emits s_waitcnt vmcnt(0)
// which would stall on global h-stores and x-prefetch every step).
__device__ __forceinline__ void barrier_lds() {
    asm volatile("s_waitcnt lgkmcnt(0)\n\ts_barrier" ::: "memory");
}

__device__ __forceinline__ float fast_sigmoid(float x) {
    float e = __expf(-x);
    return __builtin_amdgcn_rcpf(1.f + e);
}
__device__ __forceinline__ float fast_tanh(float x) {
    x = fmaxf(x, -15.f);
    float e = __expf(-2.f * x);
    return (1.f - e) * __builtin_amdgcn_rcpf(1.f + e);
}
__device__ __forceinline__ float bf2f(unsigned short u) {
    return __builtin_bit_cast(float, (unsigned)u << 16);
}

// ---------------------------------------------------------------- weight prep
__global__ void prep_w(const float* __restrict__ wihf, const float* __restrict__ wihr,
                       const float* __restrict__ whh, const float* __restrict__ bih,
                       const float* __restrict__ bhh,
                       __bf16* __restrict__ w0H, __bf16* __restrict__ w0L,
                       __bf16* __restrict__ wrH, __bf16* __restrict__ whH,
                       float* __restrict__ bias, float* __restrict__ w0f) {
    int i = blockIdx.x * 256 + threadIdx.x;
    if (i < 2 * GG * 32) {
        int k = i & 31, gd = i >> 5;
        float w = (k < 22) ? wihf[gd * 22 + k] : 0.f;
        __bf16 h = (__bf16)w;
        w0H[i] = h; w0L[i] = (__bf16)(w - (float)h);
        w0f[i] = w;
    }
    if (i < 3 * 2 * GG * 128) wrH[i] = (__bf16)wihr[i];
    if (i < 4 * 2 * GG * HH)  whH[i] = (__bf16)whh[i];
    if (i < 4 * 2 * GG)       bias[i] = bih[i] + bhh[i];
}

// ---------------------------------------------------------------- x prep, hi/lo bf16 planes (layer 0)
__global__ __launch_bounds__(256) void prep_x_ps(const float* __restrict__ x,
                                                 __bf16* __restrict__ xhi,
                                                 __bf16* __restrict__ xlo) {
    const int b = blockIdx.x;
    __shared__ float xs[22][104];
    for (int tc = 0; tc < 10; ++tc) {
        const int t0 = tc * 100;
        __syncthreads();
        for (int i = threadIdx.x; i < 22 * 100; i += 256) {
            int k = i / 100, t = i - k * 100;
            xs[k][t] = x[((size_t)b * 22 + k) * T_ + t0 + t];
        }
        __syncthreads();
        for (int i = threadIdx.x; i < 100 * 4; i += 256) {
            int t = i >> 2, p = i & 3;
            bf16x8 vh, vl;
            #pragma unroll
            for (int j = 0; j < 8; ++j) {
                int k = p * 8 + j;
                float f = (k < 22) ? xs[k][t] : 0.f;
                __bf16 h = (__bf16)f;
                vh[j] = h;
                vl[j] = (__bf16)(f - (float)h);
            }
            *(bf16x8*)(xhi + ((size_t)b * T_ + t0 + t) * 32 + p * 8) = vh;
            *(bf16x8*)(xlo + ((size_t)b * T_ + t0 + t) * 32 + p * 8) = vl;
        }
    }
}

// ---------------------------------------------------------------- x prep single bf16 plane (fallback)
__global__ __launch_bounds__(256) void prep_x_b(const float* __restrict__ x,
                                                __bf16* __restrict__ xp) {
    const int b = blockIdx.x;
    __shared__ float xs[22][104];
    for (int tc = 0; tc < 10; ++tc) {
        const int t0 = tc * 100;
        __syncthreads();
        for (int i = threadIdx.x; i < 22 * 100; i += 256) {
            int k = i / 100, t = i - k * 100;
            xs[k][t] = x[((size_t)b * 22 + k) * T_ + t0 + t];
        }
        __syncthreads();
        for (int i = threadIdx.x; i < 100 * 4; i += 256) {
            int t = i >> 2, p = i & 3;
            bf16x8 v;
            #pragma unroll
            for (int j = 0; j < 8; ++j) {
                int k = p * 8 + j;
                v[j] = (k < 22) ? (__bf16)xs[k][t] : (__bf16)0.f;
            }
            *(bf16x8*)(xp + ((size_t)b * T_ + t0 + t) * 32 + p * 8) = v;
        }
    }
}

// ---------------------------------------------------------------- MFMA fused layer, 2 chains/block (r13 shape)
// r24 = r15 RESTORED (best verified: 304us/layer, 1185us total, VGPR=120).
// r23's bench was an infra failure (container failed twice), not a kernel
// defect; resubmitting unchanged.
// Session ledger: r16 (LDS weight streaming) 315; r17 (P-fold + bias-splat)
// 332; r18/r19 (permlane c-exchange) failed correctness; r20 (R depth-1
// split) 365; r21 (1-chain/16-step, 2 blocks/CU) 355; r22 (spread flush/x +
// P-fold) 320. Structural conclusion: the step (~728cy) is simultaneously
// near the 1-wave/SIMD issue budget AND the dependency floor (barrier ->
// ds_read ~120cy -> R-MFMA chain -> serial activation -> exchange -> barrier).
// Adding loop-body instructions costs more than the ds-shadow absorbs;
// removing them at register cost stalls elsewhere; co-residency cannot help
// (wall = 1000 x per-block step latency; 2nd block only contends for issue).
// The per-step inter-wave h broadcast through LDS+barrier is structural:
// each wave owns 16/64 h-dims and needs all 64 next step.
//  - x fragments double-buffered (xfA/xfB), issued at u==0 for grp+2.
//  - cbuf replaced by ds_swizzle lane^16 c-exchange at u==3/7.
//  - h-store flush deferred into NEXT group's u==0 ds_read window.
//  - R zero-init via persistent zero quad.
template<int KCH, bool L0, bool FIN>
__global__ __launch_bounds__(256, 1) void fused_scan3(
    const __bf16* __restrict__ inA,   // (B,T,KCH*32) bf16 (hi plane if L0)
    const __bf16* __restrict__ inB,   // lo plane (iff L0)
    const __bf16* __restrict__ wihH,  // (2,256,KCH*32) bf16 hi
    const __bf16* __restrict__ wihL,  // same, lo (iff L0)
    const __bf16* __restrict__ whhH,  // (2,256,64) bf16
    const float*  __restrict__ bias,  // (2,256) f32
    __bf16* __restrict__ out,         // (B,T,128) bf16
    float* __restrict__ outF)         // (B,128) f32 last-t h (iff FIN)
{
    const int dir = blockIdx.y;
    const int b0 = blockIdx.x * 2;
    const int tid = threadIdx.x;
    const int wv = tid >> 6, lane = tid & 63;
    const int j2 = lane & 15, q = lane >> 4;
    const int ch_l = j2 >> 3;          // chain of this lane's A-row
    const int u_l = j2 & 7;            // step-in-group of this lane's A-row
    constexpr int KIN = KCH * 32;

    __shared__ __align__(16) __bf16 hbuf[2][2][80]; // [parity][chain][j pad]

    const f32x4 Z4 = (f32x4){0.f, 0.f, 0.f, 0.f};

    bf16x8 wf[4][KCH], wfl[4][L0 ? KCH : 1];
    bf16x8 whf[4][2];
    float bgate[4];
    #pragma unroll
    for (int F = 0; F < 4; ++F) {
        const int g = (F * 4 + wv) * 16 + j2;
        bgate[F] = bias[dir * GG + g];
        #pragma unroll
        for (int ks = 0; ks < KCH; ++ks) {
            wf[F][ks] = *(const bf16x8*)(wihH + ((size_t)dir * GG + g) * KIN + ks * 32 + q * 8);
            if constexpr (L0)
                wfl[F][ks] = *(const bf16x8*)(wihL + ((size_t)dir * GG + g) * KIN + ks * 32 + q * 8);
        }
        #pragma unroll
        for (int ks = 0; ks < 2; ++ks)
            whf[F][ks] = *(const bf16x8*)(whhH + ((size_t)dir * GG + g) * HH + ks * 32 + q * 8);
    }
    if (tid < 64) {
        hbuf[1][0][tid] = (__bf16)0.f;
        hbuf[1][1][tid] = (__bf16)0.f;
    }
    __syncthreads();

    // double-buffered x fragments: A holds even-group x, B holds odd-group x
    bf16x8 xfA[KCH], xfB[KCH];
    bf16x8 xlA[L0 ? KCH : 1], xlB[L0 ? KCH : 1];
    auto issue_x = [&](int grp, auto& dh, auto& dl) {
        int s = grp * 8 + u_l;
        if (s > T_ - 1) s = T_ - 1;
        int tt = dir ? (T_ - 1) - s : s;
        const __bf16* ph = inA + ((size_t)(b0 + ch_l) * T_ + tt) * KIN + q * 8;
        #pragma unroll
        for (int ks = 0; ks < KCH; ++ks)
            dh[ks] = *(const bf16x8*)(ph + ks * 32);
        if constexpr (L0) {
            const __bf16* pl = inB + ((size_t)(b0 + ch_l) * T_ + tt) * KIN + q * 8;
            #pragma unroll
            for (int ks = 0; ks < KCH; ++ks)
                dl[ks] = *(const bf16x8*)(pl + ks * 32);
        }
    };

    // ---- prologue: P for group 0 (+bias), then prefetch group 1
    f32x4 Pu[4], Pn[4];
    #pragma unroll
    for (int F = 0; F < 4; ++F) { Pu[F] = Z4; Pn[F] = Z4; }
    issue_x(0, xfA, xlA);
    #pragma unroll
    for (int ks = 0; ks < KCH; ++ks)
        #pragma unroll
        for (int F = 0; F < 4; ++F)
            Pu[F] = __builtin_amdgcn_mfma_f32_16x16x32_bf16(xfA[ks], wf[F][ks], Pu[F], 0, 0, 0);
    if constexpr (L0) {
        #pragma unroll
        for (int ks = 0; ks < KCH; ++ks)
            #pragma unroll
            for (int F = 0; F < 4; ++F)
                Pu[F] = __builtin_amdgcn_mfma_f32_16x16x32_bf16(xlA[ks], wf[F][ks], Pu[F], 0, 0, 0);
        #pragma unroll
        for (int ks = 0; ks < KCH; ++ks)
            #pragma unroll
            for (int F = 0; F < 4; ++F)
                Pu[F] = __builtin_amdgcn_mfma_f32_16x16x32_bf16(xfA[ks], wfl[F][ks], Pu[F], 0, 0, 0);
    }
    #pragma unroll
    for (int F = 0; F < 4; ++F)
        #pragma unroll
        for (int r4 = 0; r4 < 4; ++r4)
            Pu[F][r4] += bgate[F];
    issue_x(1, xfB, xlB);

    float hsave[8];
    float creg = 0.f;

    // deferred h flush for group g: 8 bf16 stores with compile-time offsets
    auto FLUSH = [&](int g) {
        const int ch = q >> 1;
        const size_t col = (size_t)dir * HH + wv * 16 + j2;
        if (dir == 0) {
            __bf16* base = out + ((size_t)(b0 + ch) * T_ + g * 8) * 128 + col;
            #pragma unroll
            for (int u = 0; u < 8; ++u)
                if ((q & 1) == (u >> 2)) base[u * 128] = (__bf16)hsave[u];
            if constexpr (FIN)
                if (g == 124 && (q & 1) == 1)
                    outF[(size_t)(b0 + ch) * 128 + col] = hsave[7];
        } else {
            __bf16* base = out + ((size_t)(b0 + ch) * T_ + ((T_ - 1) - g * 8)) * 128 + col;
            #pragma unroll
            for (int u = 0; u < 8; ++u)
                if ((q & 1) == (u >> 2)) *(base - u * 128) = (__bf16)hsave[u];
            if constexpr (FIN)
                if (g == 0 && (q & 1) == 0)
                    outF[(size_t)(b0 + ch) * 128 + col] = hsave[0];
        }
    };

    // one 8-step group; xcH/xcL = buffer holding x(grp+1) (consumed by Pn),
    // xnH/xnL = buffer to fill with x(grp+2) at u==0.
    auto GROUP = [&](int grp, auto& xcH, auto& xnH, auto& xcL, auto& xnL) {
        #pragma unroll
        for (int u = 0; u < 8; ++u) {
            const int rp = (u + 1) & 1;   // grp*8 even -> parity compile-time
            // ds_reads first...
            bf16x8 ah0 = *(const bf16x8*)&hbuf[rp][ch_l][q * 8];
            bf16x8 ah1 = *(const bf16x8*)&hbuf[rp][ch_l][32 + q * 8];

            // ...deferred flush VALU+stores fill the ds latency at u==0
            if (u == 0 && grp > 0) FLUSH(grp - 1);

            // Pn pipeline (independent -> fills ds latency)
            if constexpr (!L0) {
                const int ks = u >> 1;
                const int Fb = (u & 1) * 2;
                Pn[Fb]     = __builtin_amdgcn_mfma_f32_16x16x32_bf16(xcH[ks], wf[Fb][ks],     Pn[Fb], 0, 0, 0);
                Pn[Fb + 1] = __builtin_amdgcn_mfma_f32_16x16x32_bf16(xcH[ks], wf[Fb + 1][ks], Pn[Fb + 1], 0, 0, 0);
            } else {
                if (u == 0) {
                    #pragma unroll
                    for (int F = 0; F < 4; ++F)
                        Pn[F] = __builtin_amdgcn_mfma_f32_16x16x32_bf16(xcH[0], wf[F][0], Pn[F], 0, 0, 0);
                } else if (u == 1) {
                    #pragma unroll
                    for (int F = 0; F < 4; ++F)
                        Pn[F] = __builtin_amdgcn_mfma_f32_16x16x32_bf16(xcL[0], wf[F][0], Pn[F], 0, 0, 0);
                } else if (u == 2) {
                    #pragma unroll
                    for (int F = 0; F < 4; ++F)
                        Pn[F] = __builtin_amdgcn_mfma_f32_16x16x32_bf16(xcH[0], wfl[F][0], Pn[F], 0, 0, 0);
                }
            }

            // recurrent MFMAs: bf16 h, 4 independent depth-2 chains, zero-quad C-in
            f32x4 R[4];
            #pragma unroll
            for (int F = 0; F < 4; ++F) {
                f32x4 t = __builtin_amdgcn_mfma_f32_16x16x32_bf16(ah0, whf[F][0], Z4, 0, 0, 0);
                R[F] = __builtin_amdgcn_mfma_f32_16x16x32_bf16(ah1, whf[F][1], t, 0, 0, 0);
            }

            // x prefetch for grp+2 (fire-and-forget; consumed ~2 groups later)
            if (u == 0) issue_x(grp + 2, xnH, xnL);

            const int r = u & 3;
            const int ch = q >> 1;
            float cold = creg;
            float iv = Pu[0][r] + R[0][r];     // bias pre-folded into Pu
            float fv = Pu[1][r] + R[1][r];
            float gv = Pu[2][r] + R[2][r];
            float ov = Pu[3][r] + R[3][r];
            float cn = fast_sigmoid(fv) * cold + fast_sigmoid(iv) * fast_tanh(gv);
            float hn = fast_sigmoid(ov) * fast_tanh(cn);
            // c-handoff between q-lane-halves via lane^16 swizzle (r15-proven
            // correct and fastest variant)
            if (u == 3 || u == 7)
                creg = __builtin_bit_cast(float,
                        __builtin_amdgcn_ds_swizzle(__builtin_bit_cast(int, cn), 0x401F));
            else
                creg = cn;
            const bool owner = ((q & 1) == (u >> 2));
            if (owner) {
                hbuf[u & 1][ch][wv * 16 + j2] = (__bf16)hn;
                hsave[u] = hn;
            }
            barrier_lds();
        }
        // rotate P for next group
        #pragma unroll
        for (int F = 0; F < 4; ++F) {
            Pu[F] = Pn[F];
            Pn[F] = Z4;
            #pragma unroll
            for (int r4 = 0; r4 < 4; ++r4) Pu[F][r4] += bgate[F];
        }
    };

    for (int g2 = 0; g2 < 62; ++g2) {
        GROUP(g2 * 2,     xfB, xfA, xlB, xlA);
        GROUP(g2 * 2 + 1, xfA, xfB, xlA, xlB);
    }
    GROUP(124, xfB, xfA, xlB, xlA);
    FLUSH(124);
}

// ---------------------------------------------------------------- VALU fallback scan (r7-proven)
template<int KIN, typename TI, typename TO>
__global__ __launch_bounds__(256, 2) void scan_valu(
    const TI* __restrict__ in, const float* __restrict__ wih,
    const float* __restrict__ whh, const float* __restrict__ bias,
    TO* __restrict__ out)
{
    const int dir = blockIdx.y, bb = blockIdx.x, g = threadIdx.x;
    __shared__ __align__(16) float xs[8][KIN];
    __shared__ __align__(16) float act[256];
    __shared__ __align__(16) float hs[2][64];

    float wk[KIN], wr[64];
    {
        const float* wp = wih + (size_t)(dir * GG + g) * KIN;
        #pragma unroll
        for (int k4 = 0; k4 < KIN / 4; ++k4) {
            f32x4 v = *(const f32x4*)(wp + k4 * 4);
            wk[k4 * 4 + 0] = v.x; wk[k4 * 4 + 1] = v.y;
            wk[k4 * 4 + 2] = v.z; wk[k4 * 4 + 3] = v.w;
        }
        const float* rp = whh + (size_t)(dir * GG + g) * HH;
        #pragma unroll
        for (int j4 = 0; j4 < 16; ++j4) {
            f32x4 v = *(const f32x4*)(rp + j4 * 4);
            wr[j4 * 4 + 0] = v.x; wr[j4 * 4 + 1] = v.y;
            wr[j4 * 4 + 2] = v.z; wr[j4 * 4 + 3] = v.w;
        }
    }
    const float bg = bias[dir * GG + g];
    const bool is_g = (g >= 128 && g < 192);
    float c = 0.f;
    if (g < 64) hs[0][g] = 0.f;
    __syncthreads();

    float hreg[8];
    for (int ch = 0; ch < 125; ++ch) {
        if constexpr (KIN == 128) {
            int l = g * 4, u = l >> 7, k = l & 127;
            int s = ch * 8 + u, tt = dir ? (T_ - 1) - s : s;
            const TI* src = in + ((size_t)bb * T_ + tt) * 128 + k;
            f32x4 fv;
            if constexpr (std::is_same_v<TI, float>) fv = *(const f32x4*)src;
            else {
                ushort4 rv = *(const ushort4*)src;
                fv = (f32x4){bf2f(rv.x), bf2f(rv.y), bf2f(rv.z), bf2f(rv.w)};
            }
            *(f32x4*)&xs[u][k] = fv;
        } else {
            int u = g >> 5, k = g & 31;
            int s = ch * 8 + u, tt = dir ? (T_ - 1) - s : s;
            if constexpr (std::is_same_v<TI, float>)
                xs[u][k] = in[((size_t)bb * T_ + tt) * 32 + k];
            else
                xs[u][k] = bf2f(((const unsigned short*)in)[((size_t)bb * T_ + tt) * 32 + k]);
        }
        __syncthreads();
        #pragma unroll
        for (int u = 0; u < 8; ++u) {
            const int p = (ch * 8 + u) & 1;
            float a0 = bg, a1 = 0.f, a2 = 0.f, a3 = 0.f;
            #pragma unroll
            for (int k = 0; k < KIN; k += 4) {
                f32x4 xv = *(const f32x4*)&xs[u][k];
                a0 = fmaf(xv.x, wk[k + 0], a0); a1 = fmaf(xv.y, wk[k + 1], a1);
                a2 = fmaf(xv.z, wk[k + 2], a2); a3 = fmaf(xv.w, wk[k + 3], a3);
            }
            #pragma unroll
            for (int j = 0; j < 64; j += 4) {
                f32x4 hv = *(const f32x4*)&hs[p][j];
                a0 = fmaf(hv.x, wr[j + 0], a0); a1 = fmaf(hv.y, wr[j + 1], a1);
                a2 = fmaf(hv.z, wr[j + 2], a2); a3 = fmaf(hv.w, wr[j + 3], a3);
            }
            float a = (a0 + a1) + (a2 + a3);
            act[g] = is_g ? fast_tanh(a) : fast_sigmoid(a);
            __syncthreads();
            if (g < 64) {
                float iv = act[g], fv = act[64 + g], gv = act[128 + g], ov = act[192 + g];
                c = fmaf(fv, c, iv * gv);
                float hn = ov * fast_tanh(c);
                hs[p ^ 1][g] = hn;
                hreg[u] = hn;
            }
            __syncthreads();
        }
        if (g < 64) {
            #pragma unroll
            for (int u = 0; u < 8; ++u) {
                int s = ch * 8 + u, tt = dir ? (T_ - 1) - s : s;
                out[((size_t)bb * T_ + tt) * 128 + dir * HH + g] = (TO)hreg[u];
            }
        }
    }
}

// ---------------------------------------------------------------- heads (f32 out)
__global__ __launch_bounds__(64) void head_last(
    const float* __restrict__ hl, const float* __restrict__ wlin,
    const float* __restrict__ blin, float* __restrict__ outp) {
    const int b = blockIdx.x, tid = threadIdx.x;
    __shared__ float hv[128];
    hv[tid] = hl[(size_t)b * 128 + tid];
    hv[64 + tid] = hl[(size_t)b * 128 + 64 + tid];
    __syncthreads();
    if (tid < 54) {
        float a = blin[tid];
        #pragma unroll 4
        for (int j = 0; j < 128; ++j) a = fmaf(hv[j], wlin[tid * 128 + j], a);
        outp[b * 54 + tid] = a;
    }
}

template<typename TI>
__global__ __launch_bounds__(64) void head_kernel(
    const TI* __restrict__ fin, const float* __restrict__ wlin,
    const float* __restrict__ blin, float* __restrict__ outp) {
    const int b = blockIdx.x, tid = threadIdx.x;
    __shared__ float hv[128];
    #pragma unroll
    for (int rr = 0; rr < 2; ++rr) {
        int j = rr * 64 + tid;
        hv[j] = (float)fin[((size_t)b * T_ + (T_ - 1)) * 128 + j];
    }
    __syncthreads();
    if (tid < 54) {
        float a = blin[tid];
        #pragma unroll 4
        for (int j = 0; j < 128; ++j) a = fmaf(hv[j], wlin[tid * 128 + j], a);
        outp[b * 54 + tid] = a;
    }
}

extern "C" void kernel_launch(void* const* d_in, const int* in_sizes, int n_in,
                              void* d_out, int out_size, void* d_ws, size_t ws_size,
                              hipStream_t stream) {
    const float* x    = (const float*)d_in[0];
    const float* wihf = (const float*)d_in[1];
    const float* wihr = (const float*)d_in[2];
    const float* whh  = (const float*)d_in[3];
    const float* bih  = (const float*)d_in[4];
    const float* bhh  = (const float*)d_in[5];
    const float* wlin = (const float*)d_in[6];
    const float* blin = (const float*)d_in[7];
    float* outp = (float*)d_out;

    char* ws = (char*)d_ws;
    const size_t PB = (size_t)NB * T_ * 128 * sizeof(__bf16);  // 65,536,000
    const size_t PX = (size_t)NB * T_ * 32 * sizeof(__bf16);   // 16,384,000
    const size_t HL = (size_t)NB * 128 * sizeof(float);        //    131,072
    const size_t WSZ = 794624;
    const bool primary = ws_size >= 2 * PB + 2 * PX + HL + WSZ;  // ~164.8 MB (proven >=263)

    char* sw = primary ? (ws + 2 * PB + 2 * PX + HL) : (ws + 2 * PB);
    __bf16* w0H  = (__bf16*)(sw);             //  32,768 B
    __bf16* w0L  = (__bf16*)(sw + 32768);     //  32,768 B
    __bf16* wrH  = (__bf16*)(sw + 65536);     // 393,216 B
    __bf16* whH  = (__bf16*)(sw + 458752);    // 262,144 B
    float*  bias = (float*) (sw + 720896);    //   8,192 B
    float*  w0f  = (float*) (sw + 729088);    //  65,536 B (VALU fallback)

    prep_w<<<768, 256, 0, stream>>>(wihf, wihr, whh, bih, bhh,
                                    w0H, w0L, wrH, whH, bias, w0f);

    if (primary) {
        __bf16* A   = (__bf16*)ws;
        __bf16* B   = (__bf16*)(ws + PB);
        __bf16* xhi = (__bf16*)(ws + 2 * PB);
        __bf16* xlo = (__bf16*)(ws + 2 * PB + PX);
        float*  hl  = (float*)(ws + 2 * PB + 2 * PX);
        prep_x_ps<<<NB, 256, 0, stream>>>(x, xhi, xlo);
        const dim3 sgrid(NB / 2, 2);
        fused_scan3<1, true,  false><<<sgrid, 256, 0, stream>>>(xhi, xlo, w0H, w0L, whH, bias, A, nullptr);
        fused_scan3<4, false, false><<<sgrid, 256, 0, stream>>>(A, nullptr, wrH, nullptr,
            whH + 32768, bias + 512, B, nullptr);
        fused_scan3<4, false, false><<<sgrid, 256, 0, stream>>>(B, nullptr, wrH + 65536, nullptr,
            whH + 65536, bias + 1024, A, nullptr);
        fused_scan3<4, false, true><<<sgrid, 256, 0, stream>>>(A, nullptr, wrH + 131072, nullptr,
            whH + 98304, bias + 1536, B, hl);
        head_last<<<NB, 64, 0, stream>>>(hl, wlin, blin, outp);
    } else {
        __bf16* A = (__bf16*)ws;
        __bf16* B = (__bf16*)(ws + PB);
        __bf16* xp = (__bf16*)ws;  // aliases A; dead before A written
        prep_x_b<<<NB, 256, 0, stream>>>(x, xp);
        const dim3 vgrid(NB, 2);
        scan_valu<32, __bf16, __bf16><<<vgrid, 256, 0, stream>>>(xp, w0f, whh, bias, B);
        scan_valu<128, __bf16, __bf16><<<vgrid, 256, 0, stream>>>(B, wihr,          whh + 32768, bias + 512,  A);
        scan_valu<128, __bf16, __bf16><<<vgrid, 256, 0, stream>>>(A, wihr + 65536,  whh + 65536, bias + 1024, B);
        scan_valu<128, __bf16, __bf16><<<vgrid, 256, 0, stream>>>(B, wihr + 131072, whh + 98304, bias + 1536, A);
        head_kernel<__bf16><<<NB, 64, 0, stream>>>(A, wlin, blin, outp);
    }
}